// Round 19
// baseline (322.393 us; speedup 1.0000x reference)
//
#include <hip/hip_runtime.h>
#include <stdint.h>

#define M_DIM 4096
#define N_DIM 4096
#define K_DIM 4096

typedef int i32x4 __attribute__((ext_vector_type(4)));

// ---- Kernel 1: blocks 0..2047: W partial max -> wpmax[b]; blocks 2048..4095:
// 2 x-rows each: rowmax -> xsinv, quant -> xq (single pass, no atomics) ----
__global__ void prep1_kernel(const float* __restrict__ w,
                             const float* __restrict__ x,
                             float* __restrict__ wpmax,
                             char* __restrict__ xq,
                             float* __restrict__ xsinv) {
    __shared__ float sred[4];
    const int t = threadIdx.x;
    if (blockIdx.x < 2048) {
        int tid = blockIdx.x * 256 + t;
        const int stride = 2048 * 256;
        const int n4 = (N_DIM * K_DIM) / 4;
        const float4* w4 = (const float4*)w;
        float m = 0.f;
        for (int i = tid; i < n4; i += stride) {
            float4 a = w4[i];
            m = fmaxf(m, fmaxf(fmaxf(fabsf(a.x), fabsf(a.y)), fmaxf(fabsf(a.z), fabsf(a.w))));
        }
        for (int off = 32; off > 0; off >>= 1) m = fmaxf(m, __shfl_xor(m, off));
        if ((t & 63) == 0) sred[t >> 6] = m;
        __syncthreads();
        if (t == 0)
            wpmax[blockIdx.x] = fmaxf(fmaxf(sred[0], sred[1]), fmaxf(sred[2], sred[3]));
    } else {
        const int rbase = (blockIdx.x - 2048) * 2;
        #pragma unroll
        for (int r = 0; r < 2; ++r) {
            const int row = rbase + r;
            const float4* xr = (const float4*)(x + (size_t)row * K_DIM);
            float4 v[4];
            float m = 0.f;
            #pragma unroll
            for (int i = 0; i < 4; ++i) {
                v[i] = xr[t * 4 + i];
                m = fmaxf(m, fmaxf(fmaxf(fabsf(v[i].x), fabsf(v[i].y)),
                                   fmaxf(fabsf(v[i].z), fabsf(v[i].w))));
            }
            for (int off = 32; off > 0; off >>= 1) m = fmaxf(m, __shfl_xor(m, off));
            if ((t & 63) == 0) sred[t >> 6] = m;
            __syncthreads();
            m = fmaxf(fmaxf(fmaxf(sred[0], sred[1]), fmaxf(sred[2], sred[3])), 1e-30f);
            if (t == 0) xsinv[row] = m * (1.0f / 127.0f);
            const float scale = 127.0f / m;
            int4 o;
            int* op = (int*)&o;
            #pragma unroll
            for (int i = 0; i < 4; ++i) {
                int a = (int)rintf(v[i].x * scale);
                int b = (int)rintf(v[i].y * scale);
                int c = (int)rintf(v[i].z * scale);
                int d = (int)rintf(v[i].w * scale);
                op[i] = (a & 0xff) | ((b & 0xff) << 8) | ((c & 0xff) << 16) | (d << 24);
            }
            *(int4*)(xq + (size_t)row * K_DIM + t * 16) = o;
            __syncthreads();
        }
    }
}

// ---- Kernel 2: every block reduces wpmax (deterministic, L2-hot) -> wscale;
// grid-stride W -> int8 (trunc, exact reference grid); block 0 stores wdq ----
__global__ void prep2_kernel(const float* __restrict__ w,
                             const float* __restrict__ wpmax,
                             int* __restrict__ wq4,
                             float* __restrict__ wdq_out) {
    __shared__ float sred[4];
    const int t = threadIdx.x;
    float m = 0.f;
    #pragma unroll
    for (int i = 0; i < 8; ++i) m = fmaxf(m, wpmax[t * 8 + i]);
    for (int off = 32; off > 0; off >>= 1) m = fmaxf(m, __shfl_xor(m, off));
    if ((t & 63) == 0) sred[t >> 6] = m;
    __syncthreads();
    const float maxv = fmaxf(fmaxf(sred[0], sred[1]), fmaxf(sred[2], sred[3]));
    const float wscale = 127.0f / maxv;
    if (blockIdx.x == 0 && t == 0) *wdq_out = maxv * (1.0f / 127.0f);

    int tid = blockIdx.x * 256 + t;
    const int stride = 2048 * 256;
    const int n4 = (N_DIM * K_DIM) / 4;
    const float4* w4 = (const float4*)w;
    for (int i = tid; i < n4; i += stride) {
        float4 a = w4[i];
        int w0 = (int)fminf(fmaxf(truncf(a.x * wscale), -127.f), 127.f);
        int w1 = (int)fminf(fmaxf(truncf(a.y * wscale), -127.f), 127.f);
        int w2 = (int)fminf(fmaxf(truncf(a.z * wscale), -127.f), 127.f);
        int w3 = (int)fminf(fmaxf(truncf(a.w * wscale), -127.f), 127.f);
        wq4[i] = (w0 & 0xff) | ((w1 & 0xff) << 8) | ((w2 & 0xff) << 16) | (w3 << 24);
    }
}

// ---- Kernel 3: 256x256 i8 GEMM, R13 geometry (16x16x64, conflict-free swizzle),
// with CROSS-BARRIER MFMA DEFERRAL: iteration T issues reads(T)+stages(T+1), then
// runs MFMA for tile T-1 (register-only, zero wait), then lgkm0+vm0+BAR. Reads get
// the full MFMA window to drain; both waits are ~free. Two fragment sets (P/Q);
// accumulators in AGPRs ("+a") to keep arch-VGPR pressure in budget.
#define BAR()   __builtin_amdgcn_s_barrier()
#define FENCE() __builtin_amdgcn_sched_barrier(0)

#define MFMA_I8(ACC, AF, BF) \
    asm("v_mfma_i32_16x16x64_i8 %0, %1, %2, %0" : "+a"(ACC) : "v"(AF), "v"(BF))

__global__ __launch_bounds__(512, 2) void gemm_i8(
    const char* __restrict__ A,
    const char* __restrict__ B,
    const float* __restrict__ wdqp,
    const float* __restrict__ xsinv,
    const float* __restrict__ bias,
    float* __restrict__ C)
{
    __shared__ __align__(16) char sM[131072];

    int bid = (blockIdx.x & 7) * 32 + (blockIdx.x >> 3);   // XCD-bijective (nwg=256)
    const int bm = bid >> 4;
    const int bn = bid & 15;

    const int t    = threadIdx.x;
    const int wave = t >> 6;
    const int lane = t & 63;
    const int wm   = wave >> 2;     // 0..1
    const int wn   = wave & 3;      // 0..3

    i32x4 acc[2][2][4][2] = {};     // [h][g][mi][ni] -> AGPRs

    // LDS-read bases (swizzle folded: row&7 == lane&7 for all row-blocks used)
    const int chunk = (((lane >> 4) << 4) ^ ((lane & 7) << 4));
    const int lbA0 = ((lane & 15) << 7) + chunk + wm * 8192;
    const int lbA1 = lbA0 ^ 64;
    const int lbB0 = ((lane & 15) << 7) + chunk + wn * 4096 + 65536;
    const int lbB1 = lbB0 ^ 64;

    // Staging: thread t owns linear LDS slot t*16 (+8192 for 2nd 64-row block);
    // source chunk pre-swizzled so LDS[row][c] = SRC[row][c^(row&7)].
    const int srow = t >> 3;
    const int cch  = (t & 7) ^ (srow & 7);
    const char* Abase = A + (size_t)(bm * 256 + srow) * K_DIM + cch * 16;
    const char* Bbase = B + (size_t)(bn * 256 + srow) * K_DIM + cch * 16;
    const int wave_lds = wave * 1024;   // wave-uniform dest; HW adds lane*16

#define STAGE(SRC, REG, H, KT, BUF) do {                                                \
        const char* _s = SRC + (H) * (128 * K_DIM) + ((KT) << 7);                       \
        char* _d = sM + (REG) + (BUF) * 32768 + (H) * 16384 + wave_lds;                 \
        __builtin_amdgcn_global_load_lds(                                               \
            (const __attribute__((address_space(1))) void*)_s,                          \
            (__attribute__((address_space(3))) void*)_d, 16, 0, 0);                     \
        __builtin_amdgcn_global_load_lds(                                               \
            (const __attribute__((address_space(1))) void*)(_s + (size_t)64 * K_DIM),   \
            (__attribute__((address_space(3))) void*)(_d + 8192), 16, 0, 0);            \
    } while(0)

    // All 24 frag reads of one K-tile from BUF into set (AF0,AF1,BF0,BF1).
#define LDALL(BUF, AF0, AF1, BF0, BF1) do {                                             \
        _Pragma("unroll") for (int mi = 0; mi < 4; ++mi) {                              \
            AF0[mi][0] = *(const i32x4*)(sM + (BUF)*32768 + mi*2048 + lbA0);            \
            AF0[mi][1] = *(const i32x4*)(sM + (BUF)*32768 + mi*2048 + lbA1);            \
            AF1[mi][0] = *(const i32x4*)(sM + (BUF)*32768 + 16384 + mi*2048 + lbA0);    \
            AF1[mi][1] = *(const i32x4*)(sM + (BUF)*32768 + 16384 + mi*2048 + lbA1);    \
        }                                                                               \
        _Pragma("unroll") for (int ni = 0; ni < 2; ++ni) {                              \
            BF0[ni][0] = *(const i32x4*)(sM + (BUF)*32768 + ni*2048 + lbB0);            \
            BF0[ni][1] = *(const i32x4*)(sM + (BUF)*32768 + ni*2048 + lbB1);            \
            BF1[ni][0] = *(const i32x4*)(sM + (BUF)*32768 + 16384 + ni*2048 + lbB0);    \
            BF1[ni][1] = *(const i32x4*)(sM + (BUF)*32768 + 16384 + ni*2048 + lbB1);    \
        }                                                                               \
    } while(0)

    // Full 64-MFMA cluster (4 quadrants, kk-outer) on one fragment set.
#define MMASET(AF0, AF1, BF0, BF1) do {                                                 \
        __builtin_amdgcn_s_setprio(1);                                                  \
        _Pragma("unroll") for (int kk = 0; kk < 2; ++kk)                                \
        _Pragma("unroll") for (int mi = 0; mi < 4; ++mi)                                \
        _Pragma("unroll") for (int ni = 0; ni < 2; ++ni) {                              \
            MFMA_I8(acc[0][0][mi][ni], AF0[mi][kk], BF0[ni][kk]);                       \
            MFMA_I8(acc[0][1][mi][ni], AF0[mi][kk], BF1[ni][kk]);                       \
            MFMA_I8(acc[1][1][mi][ni], AF1[mi][kk], BF1[ni][kk]);                       \
            MFMA_I8(acc[1][0][mi][ni], AF1[mi][kk], BF0[ni][kk]);                       \
        }                                                                               \
        __builtin_amdgcn_s_setprio(0);                                                  \
    } while(0)

    // Iteration T: reads(T)->FCUR, stages(T+1 = KN)->OBUF, MFMA(T-1) on FPRV, waits, BAR.
#define TBODY(BUF, OBUF, KN, CA0, CA1, CB0, CB1, PA0, PA1, PB0, PB1) do {               \
        LDALL(BUF, CA0, CA1, CB0, CB1);          /* 24 ds_read, no consumer yet */      \
        FENCE();                                                                        \
        STAGE(Abase, 0,     0, KN, OBUF);                                               \
        STAGE(Bbase, 65536, 0, KN, OBUF);                                               \
        STAGE(Abase, 0,     1, KN, OBUF);                                               \
        STAGE(Bbase, 65536, 1, KN, OBUF);        /* 8 gload_lds */                      \
        FENCE();                                                                        \
        MMASET(PA0, PA1, PB0, PB1);              /* register-only: issues immediately */\
        FENCE();                                                                        \
        asm volatile("s_waitcnt lgkmcnt(0)");    /* reads(T) drained (had full window)*/\
        asm volatile("s_waitcnt vmcnt(0)");      /* stages(T+1) landed */               \
        BAR();                                                                          \
        FENCE();                                                                        \
    } while(0)

    i32x4 pa0[4][2], pa1[4][2], pb0[2][2], pb1[2][2];   // set P (even tiles)
    i32x4 qa0[4][2], qa1[4][2], qb0[2][2], qb1[2][2];   // set Q (odd tiles)

    // Prologue: stage tile0 -> buf0; then T=0: reads(0)->P, stages(1->buf1), no MFMA.
    STAGE(Abase, 0,     0, 0, 0);
    STAGE(Bbase, 65536, 0, 0, 0);
    STAGE(Abase, 0,     1, 0, 0);
    STAGE(Bbase, 65536, 1, 0, 0);
    asm volatile("s_waitcnt vmcnt(0)");
    BAR();
    FENCE();
    LDALL(0, pa0, pa1, pb0, pb1);
    FENCE();
    STAGE(Abase, 0,     0, 1, 1);
    STAGE(Bbase, 65536, 0, 1, 1);
    STAGE(Abase, 0,     1, 1, 1);
    STAGE(Bbase, 65536, 1, 1, 1);
    asm volatile("s_waitcnt lgkmcnt(0)");
    asm volatile("s_waitcnt vmcnt(0)");
    BAR();
    FENCE();

    // T=1 (buf1 -> Q; stage tile2 -> buf0; MFMA tile0 on P)
    TBODY(1, 0, 2, qa0, qa1, qb0, qb1, pa0, pa1, pb0, pb1);
    // T=2..31
    for (int it = 1; it < 16; ++it) {
        TBODY(0, 1, (2 * it + 1) & 31, pa0, pa1, pb0, pb1, qa0, qa1, qb0, qb1);
        TBODY(1, 0, (2 * it + 2) & 31, qa0, qa1, qb0, qb1, pa0, pa1, pb0, pb1);
    }
    // Epilogue MFMA: tile 31 (in set Q)
    MMASET(qa0, qa1, qb0, qb1);

    const float wdq = *wdqp;

    // Epilogue: D layout (m89): col = lane&15, row = (lane>>4)*4 + reg.
    // C = acc * (wdq * xsinv[row]) + bias[col]
    #pragma unroll
    for (int h = 0; h < 2; ++h)
    #pragma unroll
    for (int mi = 0; mi < 4; ++mi) {
        const int grow0 = bm * 256 + h * 128 + wm * 64 + mi * 16 + (lane >> 4) * 4;
        float rs[4];
        #pragma unroll
        for (int rg = 0; rg < 4; ++rg) rs[rg] = xsinv[grow0 + rg] * wdq;
        #pragma unroll
        for (int g = 0; g < 2; ++g)
        #pragma unroll
        for (int ni = 0; ni < 2; ++ni) {
            const int gcol = bn * 256 + g * 128 + wn * 32 + ni * 16 + (lane & 15);
            const float bv = bias[gcol];
            #pragma unroll
            for (int rg = 0; rg < 4; ++rg)
                C[(size_t)(grow0 + rg) * N_DIM + gcol] =
                    (float)acc[h][g][mi][ni][rg] * rs[rg] + bv;
        }
    }

#undef STAGE
#undef LDALL
#undef MMASET
#undef TBODY
}

extern "C" void kernel_launch(void* const* d_in, const int* in_sizes, int n_in,
                              void* d_out, int out_size, void* d_ws, size_t ws_size,
                              hipStream_t stream) {
    const float* x    = (const float*)d_in[0];   // [4096, 4096]
    const float* w    = (const float*)d_in[1];   // [4096, 4096]
    const float* bias = (const float*)d_in[2];   // [4096]
    float* out = (float*)d_out;

    float* wpmax = (float*)d_ws;                            // [2048] partial maxima
    float* wdqp  = (float*)((char*)d_ws + 8192);            // [1] wmax/127
    float* xsinv = (float*)((char*)d_ws + 8448);            // [4096]
    char*  xq    = (char*)d_ws + 32768;                     // 16 MB
    char*  wq    = (char*)d_ws + 32768 + (size_t)M_DIM * K_DIM;

    prep1_kernel<<<4096, 256, 0, stream>>>(w, x, wpmax, xq, xsinv);
    prep2_kernel<<<2048, 256, 0, stream>>>(w, wpmax, (int*)wq, wdqp);

    const int grid = (M_DIM / 256) * (N_DIM / 256);  // 256
    gemm_i8<<<grid, 512, 0, stream>>>(xq, wq, wdqp, xsinv, bias, out);
}

// Round 20
// 101.182 us; speedup vs baseline: 3.1863x; 3.1863x over previous
//
#include <hip/hip_runtime.h>
#include <stdint.h>

#define M_DIM 4096
#define N_DIM 4096
#define K_DIM 4096

typedef int i32x4 __attribute__((ext_vector_type(4)));

// ---- Kernel 1: blocks 0..2047: W partial max -> wpmax[b]; blocks 2048..4095:
// 2 x-rows each: rowmax -> xsinv, quant -> xq (single pass, no atomics) ----
__global__ void prep1_kernel(const float* __restrict__ w,
                             const float* __restrict__ x,
                             float* __restrict__ wpmax,
                             char* __restrict__ xq,
                             float* __restrict__ xsinv) {
    __shared__ float sred[4];
    const int t = threadIdx.x;
    if (blockIdx.x < 2048) {
        int tid = blockIdx.x * 256 + t;
        const int stride = 2048 * 256;
        const int n4 = (N_DIM * K_DIM) / 4;
        const float4* w4 = (const float4*)w;
        float m = 0.f;
        for (int i = tid; i < n4; i += stride) {
            float4 a = w4[i];
            m = fmaxf(m, fmaxf(fmaxf(fabsf(a.x), fabsf(a.y)), fmaxf(fabsf(a.z), fabsf(a.w))));
        }
        for (int off = 32; off > 0; off >>= 1) m = fmaxf(m, __shfl_xor(m, off));
        if ((t & 63) == 0) sred[t >> 6] = m;
        __syncthreads();
        if (t == 0)
            wpmax[blockIdx.x] = fmaxf(fmaxf(sred[0], sred[1]), fmaxf(sred[2], sred[3]));
    } else {
        const int rbase = (blockIdx.x - 2048) * 2;
        #pragma unroll
        for (int r = 0; r < 2; ++r) {
            const int row = rbase + r;
            const float4* xr = (const float4*)(x + (size_t)row * K_DIM);
            float4 v[4];
            float m = 0.f;
            #pragma unroll
            for (int i = 0; i < 4; ++i) {
                v[i] = xr[t * 4 + i];
                m = fmaxf(m, fmaxf(fmaxf(fabsf(v[i].x), fabsf(v[i].y)),
                                   fmaxf(fabsf(v[i].z), fabsf(v[i].w))));
            }
            for (int off = 32; off > 0; off >>= 1) m = fmaxf(m, __shfl_xor(m, off));
            if ((t & 63) == 0) sred[t >> 6] = m;
            __syncthreads();
            m = fmaxf(fmaxf(fmaxf(sred[0], sred[1]), fmaxf(sred[2], sred[3])), 1e-30f);
            if (t == 0) xsinv[row] = m * (1.0f / 127.0f);
            const float scale = 127.0f / m;
            int4 o;
            int* op = (int*)&o;
            #pragma unroll
            for (int i = 0; i < 4; ++i) {
                int a = (int)rintf(v[i].x * scale);
                int b = (int)rintf(v[i].y * scale);
                int c = (int)rintf(v[i].z * scale);
                int d = (int)rintf(v[i].w * scale);
                op[i] = (a & 0xff) | ((b & 0xff) << 8) | ((c & 0xff) << 16) | (d << 24);
            }
            *(int4*)(xq + (size_t)row * K_DIM + t * 16) = o;
            __syncthreads();
        }
    }
}

// ---- Kernel 2: every block reduces wpmax (deterministic, L2-hot) -> wscale;
// grid-stride W -> int8 (trunc, exact reference grid); block 0 stores wdq ----
__global__ void prep2_kernel(const float* __restrict__ w,
                             const float* __restrict__ wpmax,
                             int* __restrict__ wq4,
                             float* __restrict__ wdq_out) {
    __shared__ float sred[4];
    const int t = threadIdx.x;
    float m = 0.f;
    #pragma unroll
    for (int i = 0; i < 8; ++i) m = fmaxf(m, wpmax[t * 8 + i]);
    for (int off = 32; off > 0; off >>= 1) m = fmaxf(m, __shfl_xor(m, off));
    if ((t & 63) == 0) sred[t >> 6] = m;
    __syncthreads();
    const float maxv = fmaxf(fmaxf(sred[0], sred[1]), fmaxf(sred[2], sred[3]));
    const float wscale = 127.0f / maxv;
    if (blockIdx.x == 0 && t == 0) *wdq_out = maxv * (1.0f / 127.0f);

    int tid = blockIdx.x * 256 + t;
    const int stride = 2048 * 256;
    const int n4 = (N_DIM * K_DIM) / 4;
    const float4* w4 = (const float4*)w;
    for (int i = tid; i < n4; i += stride) {
        float4 a = w4[i];
        int w0 = (int)fminf(fmaxf(truncf(a.x * wscale), -127.f), 127.f);
        int w1 = (int)fminf(fmaxf(truncf(a.y * wscale), -127.f), 127.f);
        int w2 = (int)fminf(fmaxf(truncf(a.z * wscale), -127.f), 127.f);
        int w3 = (int)fminf(fmaxf(truncf(a.w * wscale), -127.f), 127.f);
        wq4[i] = (w0 & 0xff) | ((w1 & 0xff) << 8) | ((w2 & 0xff) << 16) | (w3 << 24);
    }
}

// ---- Kernel 3: 256x256 i8 GEMM (R6/R13: 1 barrier/K-tile, all-LDS, upfront grouped
// reads -> compiler counted-lgkm overlap). LDS 128KB: A dbuf @0/32K, B @64K/96K.
// Swizzle byte ^= (row&7)<<4 both-sides (0 bank conflicts). mfma_i32_16x16x64_i8.
#define BAR()   __builtin_amdgcn_s_barrier()
#define FENCE() __builtin_amdgcn_sched_barrier(0)

#define MFMA_I8(ACC, AF, BF) \
    asm("v_mfma_i32_16x16x64_i8 %0, %1, %2, %0" : "+v"(ACC) : "v"(AF), "v"(BF))

__global__ __launch_bounds__(512, 2) void gemm_i8(
    const char* __restrict__ A,
    const char* __restrict__ B,
    const float* __restrict__ wdqp,
    const float* __restrict__ xsinv,
    const float* __restrict__ bias,
    float* __restrict__ C)
{
    __shared__ __align__(16) char sM[131072];

    int bid = (blockIdx.x & 7) * 32 + (blockIdx.x >> 3);   // XCD-bijective (nwg=256)
    const int bm = bid >> 4;
    const int bn = bid & 15;

    const int t    = threadIdx.x;
    const int wave = t >> 6;
    const int lane = t & 63;
    const int wm   = wave >> 2;     // 0..1
    const int wn   = wave & 3;      // 0..3

    i32x4 acc[2][2][4][2] = {};     // [h][g][mi][ni]

    // LDS-read bases (swizzle folded: row&7 == lane&7 for all row-blocks used)
    const int chunk = (((lane >> 4) << 4) ^ ((lane & 7) << 4));
    const int lbA0 = ((lane & 15) << 7) + chunk + wm * 8192;
    const int lbA1 = lbA0 ^ 64;
    const int lbB0 = ((lane & 15) << 7) + chunk + wn * 4096 + 65536;
    const int lbB1 = lbB0 ^ 64;

    // Staging: thread t owns linear LDS slot t*16 (+8192 for 2nd 64-row block);
    // source chunk pre-swizzled so LDS[row][c] = SRC[row][c^(row&7)].
    const int srow = t >> 3;
    const int cch  = (t & 7) ^ (srow & 7);
    const char* Abase = A + (size_t)(bm * 256 + srow) * K_DIM + cch * 16;
    const char* Bbase = B + (size_t)(bn * 256 + srow) * K_DIM + cch * 16;
    const int wave_lds = wave * 1024;   // wave-uniform dest; HW adds lane*16

#define STAGE(SRC, REG, H, KT, BUF) do {                                                \
        const char* _s = SRC + (H) * (128 * K_DIM) + ((KT) << 7);                       \
        char* _d = sM + (REG) + (BUF) * 32768 + (H) * 16384 + wave_lds;                 \
        __builtin_amdgcn_global_load_lds(                                               \
            (const __attribute__((address_space(1))) void*)_s,                          \
            (__attribute__((address_space(3))) void*)_d, 16, 0, 0);                     \
        __builtin_amdgcn_global_load_lds(                                               \
            (const __attribute__((address_space(1))) void*)(_s + (size_t)64 * K_DIM),   \
            (__attribute__((address_space(3))) void*)(_d + 8192), 16, 0, 0);            \
    } while(0)

#define LDA(H, BUF, AF) do {                                                            \
        _Pragma("unroll") for (int mi = 0; mi < 4; ++mi) {                              \
            AF[mi][0] = *(const i32x4*)(sM + (BUF)*32768 + (H)*16384 + mi*2048 + lbA0); \
            AF[mi][1] = *(const i32x4*)(sM + (BUF)*32768 + (H)*16384 + mi*2048 + lbA1); \
        }                                                                               \
    } while(0)

#define LDB(G, BUF, BF) do {                                                            \
        _Pragma("unroll") for (int ni = 0; ni < 2; ++ni) {                              \
            BF[ni][0] = *(const i32x4*)(sM + (BUF)*32768 + (G)*16384 + ni*2048 + lbB0); \
            BF[ni][1] = *(const i32x4*)(sM + (BUF)*32768 + (G)*16384 + ni*2048 + lbB1); \
        }                                                                               \
    } while(0)

    // one C-quadrant x K=128: 16 MFMA, kk-outer (8 indep accs between acc reuse)
#define MMAQ(H, G, AF, BF)                                                              \
        _Pragma("unroll") for (int kk = 0; kk < 2; ++kk)                                \
        _Pragma("unroll") for (int mi = 0; mi < 4; ++mi)                                \
        _Pragma("unroll") for (int ni = 0; ni < 2; ++ni)                                \
            MFMA_I8(acc[H][G][mi][ni], AF[mi][kk], BF[ni][kk]);

    // One K-tile: reads from BUF, stages K-tile KN into OBUF, 64 MFMA, 1 barrier.
#define TILE(BUF, OBUF, KN) do {                                                        \
        LDA(0, BUF, af0); LDB(0, BUF, bf0);      /* 12 reads for Q(0,0) */              \
        FENCE();                                                                        \
        LDB(1, BUF, bf1);                        /* 4 reads */                          \
        STAGE(Abase, 0,     0, KN, OBUF);                                               \
        STAGE(Bbase, 65536, 0, KN, OBUF);                                               \
        STAGE(Abase, 0,     1, KN, OBUF);                                               \
        STAGE(Bbase, 65536, 1, KN, OBUF);                                               \
        LDA(1, BUF, af1);                        /* 8 reads */                          \
        FENCE();                                                                        \
        __builtin_amdgcn_s_setprio(1);                                                  \
        MMAQ(0, 0, af0, bf0);                                                           \
        MMAQ(0, 1, af0, bf1);                                                           \
        MMAQ(1, 1, af1, bf1);                                                           \
        MMAQ(1, 0, af1, bf0);                                                           \
        __builtin_amdgcn_s_setprio(0);                                                  \
        asm volatile("s_waitcnt vmcnt(0)");      /* stages issued ~2600cy ago */        \
        BAR();                                                                          \
        FENCE();                                                                        \
    } while(0)

    // Prologue: stage tile 0 -> buf0 only.
    STAGE(Abase, 0,     0, 0, 0);
    STAGE(Bbase, 65536, 0, 0, 0);
    STAGE(Abase, 0,     1, 0, 0);
    STAGE(Bbase, 65536, 1, 0, 0);
    asm volatile("s_waitcnt vmcnt(0)");
    BAR();
    FENCE();

    i32x4 af0[4][2], af1[4][2], bf0[2][2], bf1[2][2];

    for (int it = 0; it < 16; ++it) {
        TILE(0, 1, (2 * it + 1) & 31);
        TILE(1, 0, (2 * it + 2) & 31);
    }

    const float wdq = *wdqp;

    // Epilogue: D layout (m89): col = lane&15, row = (lane>>4)*4 + reg.
    // C = acc * (wdq * xsinv[row]) + bias[col]
    #pragma unroll
    for (int h = 0; h < 2; ++h)
    #pragma unroll
    for (int mi = 0; mi < 4; ++mi) {
        const int grow0 = bm * 256 + h * 128 + wm * 64 + mi * 16 + (lane >> 4) * 4;
        float rs[4];
        #pragma unroll
        for (int rg = 0; rg < 4; ++rg) rs[rg] = xsinv[grow0 + rg] * wdq;
        #pragma unroll
        for (int g = 0; g < 2; ++g)
        #pragma unroll
        for (int ni = 0; ni < 2; ++ni) {
            const int gcol = bn * 256 + g * 128 + wn * 32 + ni * 16 + (lane & 15);
            const float bv = bias[gcol];
            #pragma unroll
            for (int rg = 0; rg < 4; ++rg)
                C[(size_t)(grow0 + rg) * N_DIM + gcol] =
                    (float)acc[h][g][mi][ni][rg] * rs[rg] + bv;
        }
    }

#undef STAGE
#undef LDA
#undef LDB
#undef MMAQ
#undef TILE
}

extern "C" void kernel_launch(void* const* d_in, const int* in_sizes, int n_in,
                              void* d_out, int out_size, void* d_ws, size_t ws_size,
                              hipStream_t stream) {
    const float* x    = (const float*)d_in[0];   // [4096, 4096]
    const float* w    = (const float*)d_in[1];   // [4096, 4096]
    const float* bias = (const float*)d_in[2];   // [4096]
    float* out = (float*)d_out;

    float* wpmax = (float*)d_ws;                            // [2048] partial maxima
    float* wdqp  = (float*)((char*)d_ws + 8192);            // [1] wmax/127
    float* xsinv = (float*)((char*)d_ws + 8448);            // [4096]
    char*  xq    = (char*)d_ws + 32768;                     // 16 MB
    char*  wq    = (char*)d_ws + 32768 + (size_t)M_DIM * K_DIM;

    prep1_kernel<<<4096, 256, 0, stream>>>(w, x, wpmax, xq, xsinv);
    prep2_kernel<<<2048, 256, 0, stream>>>(w, wpmax, (int*)wq, wdqp);

    const int grid = (M_DIM / 256) * (N_DIM / 256);  // 256
    gemm_i8<<<grid, 512, 0, stream>>>(xq, wq, wdqp, xsinv, bias, out);
}